// Round 1
// baseline (82.627 us; speedup 1.0000x reference)
//
#include <hip/hip_runtime.h>
#include <hip/hip_bf16.h>

#define B_ 32
#define D_ 64
#define N_ 8
#define S_ 128
#define EPS_ 1e-6f
#define STRIDE 65          // padded LDS row stride (65 % 32 == 1 -> conflict-free columns)
#define NTHREADS 1024
#define NWAVES 16          // 1024 / 64
#define K_TERMS 7          // Taylor terms for expm; ||X|| ~ 0.02-0.05 -> error ~1e-13

__launch_bounds__(NTHREADS)
__global__ void htg_kernel(const float* __restrict__ z0,
                           const float* __restrict__ time_steps,
                           const float* __restrict__ k_coeffs,
                           const float* __restrict__ r_coeffs,
                           const float* __restrict__ alpha_p,
                           const float* __restrict__ beta_p,
                           const float* __restrict__ K_bases,
                           const float* __restrict__ R_bases,
                           float* __restrict__ out,
                           int interleaved)
{
    // LDS: 3 padded 64x64 matrices + 64-float z0 = 12544 floats = 49 KB
    __shared__ float smem[3 * D_ * STRIDE + D_];
    float* matA = smem;                    // X (generator), later Mc ping
    float* matB = smem + D_ * STRIDE;      // K_sum, later Horner P ping, later M, overlaid by zc
    float* matC = smem + 2 * D_ * STRIDE;  // R_sum, later Horner P pong, later Mc pong
    float* zc   = smem + D_ * STRIDE;      // 64 cols x 64 floats = 4096 (fits inside matB's 4160)
    float* z0s  = smem + 3 * D_ * STRIDE;  // 64 floats

    const int tid  = threadIdx.x;
    const int b    = blockIdx.x;
    const int wave = tid >> 6;
    const int lane = tid & 63;
    const int i4   = 4 * wave;             // this wave's 4 output rows in matmuls

    // ---- load per-batch scalars ----
    float kc[N_], rc[N_];
#pragma unroll
    for (int n = 0; n < N_; ++n) {
        kc[n] = k_coeffs[b * N_ + n];
        rc[n] = r_coeffs[b * N_ + n];
    }
    const float alpha = alpha_p[b];
    const float beta  = beta_p[b];
    const float dt    = time_steps[0];     // uniform grid (guaranteed by setup)

    if (tid < D_) z0s[tid] = z0[b * D_ + tid];

    // ---- Phase A: K_sum -> matB, R_sum -> matC ----
    for (int e = tid; e < D_ * D_; e += NTHREADS) {
        const int i = e >> 6, j = e & 63;
        float ks = 0.f, rs = 0.f;
#pragma unroll
        for (int n = 0; n < N_; ++n) {
            ks = fmaf(kc[n], K_bases[n * D_ * D_ + e], ks);
            rs = fmaf(rc[n], R_bases[n * D_ * D_ + e], rs);
        }
        matB[i * STRIDE + j] = ks;
        matC[i * STRIDE + j] = rs;
    }
    __syncthreads();

    // ---- Phase B: X = dt*(alpha*(K - K^T) - beta*(R^T R)) + eps*I -> matA ----
    {
        const int j = lane;
        float acc[4] = {0.f, 0.f, 0.f, 0.f};
#pragma unroll 4
        for (int k = 0; k < D_; ++k) {
            const float rkj = matC[k * STRIDE + j];      // coalesced
#pragma unroll
            for (int r = 0; r < 4; ++r)                  // broadcast reads
                acc[r] = fmaf(matC[k * STRIDE + i4 + r], rkj, acc[r]);
        }
#pragma unroll
        for (int r = 0; r < 4; ++r) {
            const int i = i4 + r;
            const float sk = matB[i * STRIDE + j] - matB[j * STRIDE + i];
            float x = dt * (alpha * sk - beta * acc[r]);
            if (i == j) x += EPS_;
            matA[i * STRIDE + j] = x;
        }
    }
    __syncthreads();

    // ---- Phase C: M = expm(X) via Horner Taylor: P = I + X/K; P = I + X*P/k ----
    for (int e = tid; e < D_ * D_; e += NTHREADS) {
        const int i = e >> 6, j = e & 63;
        float v = matA[i * STRIDE + j] * (1.f / (float)K_TERMS);
        if (i == j) v += 1.f;
        matB[i * STRIDE + j] = v;
    }
    __syncthreads();

    {
        float* src = matB;
        float* dst = matC;
        for (int k = K_TERMS - 1; k >= 1; --k) {
            const int j = lane;
            float acc[4] = {0.f, 0.f, 0.f, 0.f};
#pragma unroll 4
            for (int kk = 0; kk < D_; ++kk) {
                const float bkj = src[kk * STRIDE + j];  // coalesced
#pragma unroll
                for (int r = 0; r < 4; ++r)              // broadcast (row-contig -> b128)
                    acc[r] = fmaf(matA[(i4 + r) * STRIDE + kk], bkj, acc[r]);
            }
            const float inv = 1.f / (float)k;
#pragma unroll
            for (int r = 0; r < 4; ++r) {
                const int i = i4 + r;
                float v = acc[r] * inv;
                if (i == j) v += 1.f;
                dst[i * STRIDE + j] = v;
            }
            __syncthreads();
            float* t = src; src = dst; dst = t;
        }
        // K_TERMS=7 -> 6 iterations -> final M sits in matB
    }

    // ---- Phase D0: Mc = M (copy matB -> matA); col0 = M * z0 ----
    for (int e = tid; e < D_ * D_; e += NTHREADS) {
        const int i = e >> 6, j = e & 63;
        matA[i * STRIDE + j] = matB[i * STRIDE + j];
    }
    float c0 = 0.f;
    if (tid < D_) {
#pragma unroll 4
        for (int i = 0; i < D_; ++i)
            c0 = fmaf(matB[tid * STRIDE + i], z0s[i], c0);
    }
    __syncthreads();   // all reads of matB done; zc may now overlay it

    if (tid < D_) {
        zc[tid] = c0;  // column 0
        const size_t oi = ((size_t)b * S_ + 0) * D_ + tid;
        if (interleaved) { out[2 * oi] = c0; out[2 * oi + 1] = 0.f; }
        else             { out[oi] = c0; }
    }
    __syncthreads();

    // ---- Phase D: doubling. cols[c..2c-1] = Mc * cols[0..c-1]; Mc <- Mc^2 ----
    {
        float* mc  = matA;
        float* msq = matC;
        for (int c = 1; c < S_; c <<= 1) {
            const int nnew = c;  // S_=128, c<=64 -> always c new columns
            // apply: each wave takes columns round-robin
            for (int cc = wave; cc < nnew; cc += NWAVES) {
                const int sdst = c + cc;
                float acc = 0.f;
#pragma unroll 4
                for (int i = 0; i < D_; ++i)   // mc row per-lane (b128), zc broadcast
                    acc = fmaf(mc[lane * STRIDE + i], zc[cc * D_ + i], acc);
                const size_t oi = ((size_t)b * S_ + sdst) * D_ + lane;
                if (interleaved) { out[2 * oi] = acc; out[2 * oi + 1] = 0.f; }
                else             { out[oi] = acc; }
                if (sdst < 64) zc[sdst * D_ + lane] = acc;
            }
            // square Mc (skip after last apply)
            if (c < 64) {
                const int j = lane;
                float acc[4] = {0.f, 0.f, 0.f, 0.f};
#pragma unroll 4
                for (int kk = 0; kk < D_; ++kk) {
                    const float bkj = mc[kk * STRIDE + j];
#pragma unroll
                    for (int r = 0; r < 4; ++r)
                        acc[r] = fmaf(mc[(i4 + r) * STRIDE + kk], bkj, acc[r]);
                }
#pragma unroll
                for (int r = 0; r < 4; ++r)
                    msq[(i4 + r) * STRIDE + j] = acc[r];
            }
            __syncthreads();
            float* t = mc; mc = msq; msq = t;
        }
    }
}

extern "C" void kernel_launch(void* const* d_in, const int* in_sizes, int n_in,
                              void* d_out, int out_size, void* d_ws, size_t ws_size,
                              hipStream_t stream) {
    const float* z0         = (const float*)d_in[0];
    const float* time_steps = (const float*)d_in[1];
    const float* k_coeffs   = (const float*)d_in[2];
    const float* r_coeffs   = (const float*)d_in[3];
    const float* alpha      = (const float*)d_in[4];
    const float* beta       = (const float*)d_in[5];
    const float* K_bases    = (const float*)d_in[6];
    const float* R_bases    = (const float*)d_in[7];
    float* out = (float*)d_out;

    const int n_z = B_ * S_ * D_;                     // 262144 complex values
    const int interleaved = (out_size >= 2 * n_z) ? 1 : 0;

    htg_kernel<<<dim3(B_), dim3(NTHREADS), 0, stream>>>(
        z0, time_steps, k_coeffs, r_coeffs, alpha, beta, K_bases, R_bases,
        out, interleaved);
}

// Round 2
// 35.292 us; speedup vs baseline: 2.3413x; 2.3413x over previous
//
#include <hip/hip_runtime.h>

#define BATCH 32
#define DD 64
#define NN 8
#define SS 128
#define EPS_ 1e-6f
#define GROUPS 8          // groups per batch; each owns 16 consecutive steps
#define GSTEP 16
#define NTHREADS 1024
#define NWAVES 16

// Taylor deg-6 coefficients for exp(X):  P0 = c0+c1X+c2X2+c3X3 ; P1 = c4X+c5X2+c6X3
#define C2 0.5f
#define C3 (1.f/6.f)
#define C4 (1.f/24.f)
#define C5 (1.f/120.f)
#define C6 (1.f/720.f)
// exp(16X) = Q0 + X3*Q1 with qk = 16^k/k!  (powers of 16X are scalar multiples of X^k)
#define Q1_ 16.f
#define Q2_ 128.f
#define Q3_ 682.66666667f
// Q1mat = A_*P1 + B2_*X2 + B3_*X3   (exact linear combo, no X needed)
#define A_ 65536.f
#define B2_ 8192.f
#define B3_ 23210.66666667f

// generic C-rows matmul: this wave's rows i4..i4+3 of A*B accumulated into acc[4]
// A rows read as broadcast float4 (ds_read_b128, uniform addr), B columns coalesced b32.
__device__ __forceinline__ void mm_rows(const float* __restrict__ A,
                                        const float* __restrict__ Bm,
                                        float acc[4], int i4, int j)
{
#pragma unroll 4
    for (int kc = 0; kc < DD; kc += 4) {
        float4 a0 = *(const float4*)&A[(i4 + 0) * DD + kc];
        float4 a1 = *(const float4*)&A[(i4 + 1) * DD + kc];
        float4 a2 = *(const float4*)&A[(i4 + 2) * DD + kc];
        float4 a3 = *(const float4*)&A[(i4 + 3) * DD + kc];
        float bv0 = Bm[(kc + 0) * DD + j];
        float bv1 = Bm[(kc + 1) * DD + j];
        float bv2 = Bm[(kc + 2) * DD + j];
        float bv3 = Bm[(kc + 3) * DD + j];
        acc[0] = fmaf(a0.x, bv0, fmaf(a0.y, bv1, fmaf(a0.z, bv2, fmaf(a0.w, bv3, acc[0]))));
        acc[1] = fmaf(a1.x, bv0, fmaf(a1.y, bv1, fmaf(a1.z, bv2, fmaf(a1.w, bv3, acc[1]))));
        acc[2] = fmaf(a2.x, bv0, fmaf(a2.y, bv1, fmaf(a2.z, bv2, fmaf(a2.w, bv3, acc[2]))));
        acc[3] = fmaf(a3.x, bv0, fmaf(a3.y, bv1, fmaf(a3.z, bv2, fmaf(a3.w, bv3, acc[3]))));
    }
}

// block-wide matvec: out[i] = sum_k Mat[i][k]*v[k]; thread (mi,mh): row mi, k-chunk 4*mh
// returns full row-sum on all 16 lanes of the row-group (butterfly reduce)
__device__ __forceinline__ float mv_step(const float* __restrict__ Mat,
                                         const float* __restrict__ vsrc,
                                         int mi, int mh)
{
    float4 m = *(const float4*)&Mat[mi * DD + 4 * mh];
    float4 v = *(const float4*)&vsrc[4 * mh];
    float p = fmaf(m.x, v.x, fmaf(m.y, v.y, fmaf(m.z, v.z, m.w * v.w)));
    p += __shfl_xor(p, 1, 16);
    p += __shfl_xor(p, 2, 16);
    p += __shfl_xor(p, 4, 16);
    p += __shfl_xor(p, 8, 16);
    return p;
}

__launch_bounds__(NTHREADS)
__global__ void htg_kernel(const float* __restrict__ z0,
                           const float* __restrict__ time_steps,
                           const float* __restrict__ k_coeffs,
                           const float* __restrict__ r_coeffs,
                           const float* __restrict__ alpha_p,
                           const float* __restrict__ beta_p,
                           const float* __restrict__ K_bases,
                           const float* __restrict__ R_bases,
                           float* __restrict__ out,
                           int interleaved)
{
    __shared__ float b0[DD * DD];   // Ksum(swz) -> X2
    __shared__ float b1[DD * DD];   // Rsum -> X3 -> M
    __shared__ float b2[DD * DD];   // X -> P1 -> Q1 -> M16
    __shared__ float vb[2][DD];
    __shared__ float z0s[DD];

    const int tid  = threadIdx.x;
    const int bg   = blockIdx.x;
    const int b    = bg >> 3;       // batch
    const int g    = bg & 7;        // step-group: s in [16g, 16g+16)
    const int wave = tid >> 6;
    const int lane = tid & 63;
    const int i4   = wave * 4;
    const int j    = lane;
    const int mi   = tid >> 4;      // matvec row
    const int mh   = tid & 15;      // matvec k-chunk

    const float alpha = alpha_p[b];
    const float beta  = beta_p[b];
    const float dt    = time_steps[0];   // uniform grid
    float kc[NN], rc[NN];
#pragma unroll
    for (int n = 0; n < NN; ++n) {
        kc[n] = k_coeffs[b * NN + n];
        rc[n] = r_coeffs[b * NN + n];
    }
    if (tid < DD) z0s[tid] = z0[b * DD + tid];

    // ---- Phase A: Ksum (XOR-swizzled) -> b0, Rsum -> b1 ----
    {
        const int i  = tid >> 4;
        const int j0 = (tid & 15) * 4;
        const int e4 = i * DD + j0;
        float4 ks = make_float4(0.f, 0.f, 0.f, 0.f);
        float4 rs = make_float4(0.f, 0.f, 0.f, 0.f);
#pragma unroll
        for (int n = 0; n < NN; ++n) {
            float4 kb = *(const float4*)&K_bases[n * DD * DD + e4];
            float4 rb = *(const float4*)&R_bases[n * DD * DD + e4];
            ks.x = fmaf(kc[n], kb.x, ks.x); ks.y = fmaf(kc[n], kb.y, ks.y);
            ks.z = fmaf(kc[n], kb.z, ks.z); ks.w = fmaf(kc[n], kb.w, ks.w);
            rs.x = fmaf(rc[n], rb.x, rs.x); rs.y = fmaf(rc[n], rb.y, rs.y);
            rs.z = fmaf(rc[n], rb.z, rs.z); rs.w = fmaf(rc[n], rb.w, rs.w);
        }
        const int c = i & 31;   // swizzle: addr(i,j) = i*64 + (j^c); col reads conflict-free
        b0[i * DD + ((j0 + 0) ^ c)] = ks.x;
        b0[i * DD + ((j0 + 1) ^ c)] = ks.y;
        b0[i * DD + ((j0 + 2) ^ c)] = ks.z;
        b0[i * DD + ((j0 + 3) ^ c)] = ks.w;
        *(float4*)&b1[e4] = rs;
    }
    __syncthreads();

    // ---- MM1: X -> b2.  X = dt*(alpha*(K-K^T) - beta*(R^T R)) + eps*I ----
    {
        float acc[4] = {0.f, 0.f, 0.f, 0.f};
#pragma unroll 8
        for (int k = 0; k < DD; ++k) {
            float rk = b1[k * DD + j];           // coalesced row of Rsum
#pragma unroll
            for (int r = 0; r < 4; ++r) {        // (R^T R)[i][j] = sum_k R[k][i]*R[k][j]
                float ar = __uint_as_float(__builtin_amdgcn_readlane(__float_as_uint(rk), i4 + r));
                acc[r] = fmaf(ar, rk, acc[r]);
            }
        }
#pragma unroll
        for (int r = 0; r < 4; ++r) {
            const int i = i4 + r;
            float kij = b0[i * DD + (j ^ (i & 31))];
            float kji = b0[j * DD + (i ^ (j & 31))];
            float x = dt * (alpha * (kij - kji) - beta * acc[r]);
            if (i == j) x += EPS_;
            acc[r] = x;
        }
#pragma unroll
        for (int r = 0; r < 4; ++r) b2[(i4 + r) * DD + j] = acc[r];
    }
    __syncthreads();

    // ---- MM2: X2 = X*X -> b0 ----
    {
        float acc[4] = {0.f, 0.f, 0.f, 0.f};
        mm_rows(b2, b2, acc, i4, j);
#pragma unroll
        for (int r = 0; r < 4; ++r) b0[(i4 + r) * DD + j] = acc[r];
    }
    __syncthreads();

    // ---- MM3: X3 = X2*X -> b1 ----
    {
        float acc[4] = {0.f, 0.f, 0.f, 0.f};
        mm_rows(b0, b2, acc, i4, j);
#pragma unroll
        for (int r = 0; r < 4; ++r) b1[(i4 + r) * DD + j] = acc[r];
    }
    __syncthreads();

    // ---- preload epilogues P0 (for M) and Q0 (for M16) ----
    float accM[4], accQ[4];
#pragma unroll
    for (int r = 0; r < 4; ++r) {
        const int i = i4 + r;
        float x  = b2[i * DD + j];
        float x2 = b0[i * DD + j];
        float x3 = b1[i * DD + j];
        float d  = (i == j) ? 1.f : 0.f;
        accM[r] = d + x + C2 * x2 + C3 * x3;
        accQ[r] = d + Q1_ * x + Q2_ * x2 + Q3_ * x3;
    }
    __syncthreads();   // all preload reads of X done before P1 overwrites b2

    // ---- P1 = c4*X + c5*X2 + c6*X3  (in place over X, b2) ----
    {
        const int e4 = tid * 4;
        float4 x  = *(const float4*)&b2[e4];
        float4 x2 = *(const float4*)&b0[e4];
        float4 x3 = *(const float4*)&b1[e4];
        float4 p1;
        p1.x = C4 * x.x + C5 * x2.x + C6 * x3.x;
        p1.y = C4 * x.y + C5 * x2.y + C6 * x3.y;
        p1.z = C4 * x.z + C5 * x2.z + C6 * x3.z;
        p1.w = C4 * x.w + C5 * x2.w + C6 * x3.w;
        *(float4*)&b2[e4] = p1;
    }
    __syncthreads();

    // ---- MM4: M = P0 + X3*P1  (A=b1, B=b2), result stays in accM ----
    mm_rows(b1, b2, accM, i4, j);
    __syncthreads();   // all reads of P1 done before Q1 overwrite

    // ---- Q1 = A_*P1 + B2_*X2 + B3_*X3  (in place over b2) ----
    {
        const int e4 = tid * 4;
        float4 p1 = *(const float4*)&b2[e4];
        float4 x2 = *(const float4*)&b0[e4];
        float4 x3 = *(const float4*)&b1[e4];
        float4 q1;
        q1.x = A_ * p1.x + B2_ * x2.x + B3_ * x3.x;
        q1.y = A_ * p1.y + B2_ * x2.y + B3_ * x3.y;
        q1.z = A_ * p1.z + B2_ * x2.z + B3_ * x3.z;
        q1.w = A_ * p1.w + B2_ * x2.w + B3_ * x3.w;
        *(float4*)&b2[e4] = q1;
    }
    __syncthreads();

    // ---- MM5: M16 = Q0 + X3*Q1  (A=b1, B=b2), result in accQ ----
    mm_rows(b1, b2, accQ, i4, j);
    __syncthreads();   // all reads of b1/b2 done before overwriting with M/M16

    // ---- store M -> b1, M16 -> b2 ----
#pragma unroll
    for (int r = 0; r < 4; ++r) {
        b1[(i4 + r) * DD + j] = accM[r];
        b2[(i4 + r) * DD + j] = accQ[r];
    }
    if (tid < DD) vb[0][tid] = z0s[tid];
    __syncthreads();

    // ---- base: v = (M16)^g * z0  (g <= 7 block-wide matvecs) ----
    int pp = 0;
    for (int a = 0; a < g; ++a) {
        float val = mv_step(b2, vb[pp], mi, mh);
        if (mh == 0) vb[pp ^ 1][mi] = val;
        __syncthreads();
        pp ^= 1;
    }

    // ---- chain: 16 steps with M; emit s = 16g + t ----
    for (int t = 0; t < GSTEP; ++t) {
        float val = mv_step(b1, vb[pp], mi, mh);
        if (mh == 0) {
            vb[pp ^ 1][mi] = val;
            const int s = g * GSTEP + t;
            const size_t oi = ((size_t)(b * SS + s)) * DD + mi;
            if (interleaved) ((float2*)out)[oi] = make_float2(val, 0.f);
            else             out[oi] = val;
        }
        __syncthreads();
        pp ^= 1;
    }
}

extern "C" void kernel_launch(void* const* d_in, const int* in_sizes, int n_in,
                              void* d_out, int out_size, void* d_ws, size_t ws_size,
                              hipStream_t stream) {
    const float* z0         = (const float*)d_in[0];
    const float* time_steps = (const float*)d_in[1];
    const float* k_coeffs   = (const float*)d_in[2];
    const float* r_coeffs   = (const float*)d_in[3];
    const float* alpha      = (const float*)d_in[4];
    const float* beta       = (const float*)d_in[5];
    const float* K_bases    = (const float*)d_in[6];
    const float* R_bases    = (const float*)d_in[7];
    float* out = (float*)d_out;

    const int n_z = BATCH * SS * DD;
    const int interleaved = (out_size >= 2 * n_z) ? 1 : 0;

    htg_kernel<<<dim3(BATCH * GROUPS), dim3(NTHREADS), 0, stream>>>(
        z0, time_steps, k_coeffs, r_coeffs, alpha, beta, K_bases, R_bases,
        out, interleaved);
}